// Round 14
// baseline (133.318 us; speedup 1.0000x reference)
//
#include <hip/hip_runtime.h>

#define L2E 1.4426950408889634f
#define LN2 0.6931471805599453f

typedef float f32x16 __attribute__((ext_vector_type(16)));
typedef float f32x2  __attribute__((ext_vector_type(2)));
typedef short bf16x8 __attribute__((ext_vector_type(8)));
typedef unsigned int u32x4 __attribute__((ext_vector_type(4)));

__device__ __forceinline__ float dexp2(float x) { return __builtin_amdgcn_exp2f(x); }
__device__ __forceinline__ float dlog2(float x) { return __builtin_amdgcn_logf(x); }

// HW packed f32->2xbf16 (RNE). Inputs must be IR-produced VALU values
// (never raw MFMA accumulator regs) -- R3 post-mortem.
__device__ __forceinline__ unsigned cvtpk(float a, float b) {
    unsigned r;
    asm("v_cvt_pk_bf16_f32 %0, %1, %2" : "=v"(r) : "v"(a), "v"(b));
    return r;
}

// Software RNE pack (pure IR); low 16 bits = bf16(a).
__device__ __forceinline__ unsigned pkrne(float a, float b) {
    unsigned ua = __float_as_uint(a), ub = __float_as_uint(b);
    ua += 0x7FFFu + ((ua >> 16) & 1u);
    ub += 0x7FFFu + ((ub >> 16) & 1u);
    return __builtin_amdgcn_perm(ub, ua, 0x07060302u);
}

// CRF forward, rank-1 collapsed chunks with PERRON-SAFE anchors:
//   After 32 matrix steps (R8-verbatim), R ~= u v^T / s with
//   u = R*1 (row sums, shfl-reduce), w = 1^T R (col sums, ones-MFMA),
//   s = sum(w), v = w/s. R13's col0/row0 anchors amplified the rank-1
//   residual by 1/u1[0],1/v1[0] (Perron entries span e^+-4) -> heavy-tail
//   failures. Sum-anchors bound contamination by sigma2/sigma1 only.
// Vector phase (96 steps): u <- E*(d o u) with PER-STEP wave-max
// normalization of w = d o u (w can reach 2^51 in 4 steps; fp8 saturates
// at 448), w broadcast as fp8 in a half-permuted layout so each lane's
// 16 values are ONE ds_read_b128 (aligns exactly with efv's column order).
__global__ __launch_bounds__(1024, 4) void crf_phase_kernel(
    const float* __restrict__ em,   // [512][2048][32]
    const float* __restrict__ tr,   // [32][32] transitions[tag][prev]
    const int*   __restrict__ tgs,  // [512][2048]
    float*       __restrict__ ws)   // [512] per-batch nll
{
    __shared__ float s_tr[1024];                      // 4 KB
    __shared__ unsigned s_d8[16 * 64];                // 4 KB fp8 d staging
    __shared__ __align__(16) unsigned char s_w8[16 * 32];  // 512 B w broadcast
    __shared__ float s_u[16 * 32];                    // u handoff
    __shared__ float s_v[16 * 32];                    // v per chunk
    __shared__ float s_uf[16 * 32];                   // final u per chunk
    __shared__ float s_base[16];
    __shared__ float s_gold[16];

    const int tid = threadIdx.x;
    const int b   = blockIdx.x;
    const int w   = tid >> 6;    // wave = chunk index 0..15
    const int l   = tid & 63;
    const int h   = l >> 5;
    const int q   = l & 31;

    s_tr[tid & 1023] = tr[tid & 1023];
    __syncthreads();

    // A master: efv[j] = (E[q,col], E[q,col+1]), pi'd layout (R5-R8).
    f32x2 efv[8];
    unsigned ea[8];
#pragma unroll
    for (int j = 0; j < 8; ++j) {
        int k0  = 16 * (j >> 2) + 8 * h + 2 * (j & 3);
        int col = (k0 & ~12) | ((k0 & 4) << 1) | ((k0 & 8) >> 1);
        efv[j].x = dexp2(s_tr[q * 32 + col] * L2E);
        efv[j].y = dexp2(s_tr[q * 32 + col + 1] * L2E);
        ea[j] = pkrne(efv[j].x, efv[j].y);
    }
    const bf16x8 A0 = __builtin_bit_cast(bf16x8, (u32x4){ea[0], ea[1], ea[2], ea[3]});
    const bf16x8 A1 = __builtin_bit_cast(bf16x8, (u32x4){ea[4], ea[5], ea[6], ea[7]});

    f32x16 zro;
#pragma unroll
    for (int z = 0; z < 16; ++z) zro[z] = 0.f;

    const float* ebase = em + ((size_t)b * 2048 + (size_t)w * 128) * 32;
    const int*   tgp   = tgs + (size_t)b * 2048;

    // d[q] fetch: dword dhD of a slot, byte (q&3)
    const int dhD   = (q >> 3) + 4 * ((q >> 2) & 1);
    const int dhsh  = (q & 3) << 3;
    // w fp8 permuted write address: half ((q>>2)&1), dword (q>>3), byte (q&3)
    const int wperm = 16 * ((q >> 2) & 1) + 4 * (q >> 3) + (q & 3);

    f32x16 acc;
    float  s_cur = 1.f;
    int    k_pend = 0, sigma = 0;
    float  gold = 0.f;
    float  u_own = 0.f;
    float4 r0, r1;
    int    tregC = 0, tlastC = 0, tregN = 0, tlastN = 0;

#pragma unroll
    for (int r = 0; r < 16; ++r)
        acc[r] = ((((r & 3) + 8 * (r >> 2) + 4 * h) == q) ? 1.f : 0.f);

    auto eload = [&](int blk) -> float4 {
        int bb2 = blk > 15 ? 15 : blk;
        return *(const float4*)(ebase + ((bb2 * 8 + (l >> 3)) * 32 + (l & 7) * 4));
    };
    auto tagload = [&](int cl, int& treg, int& tlast) {
        int c0 = w * 128 + cl * 64;
        int idx = c0 - 1 + l; if (idx < 0) idx = 0;
        treg  = tgp[idx];
        tlast = tgp[c0 + 63];
    };

    r0 = eload(0); r1 = eload(1);
    tagload(0, tregC, tlastC);

#pragma unroll 1
    for (int blk = 0; blk < 16; ++blk) {
        if ((blk & 7) == 0) {
            int cl = blk >> 3;
            int cg = w * 2 + cl;
            if (cl > 0) { tregC = tregN; tlastC = tlastN; }
            {   // gold transition terms for this 64-group
                int scur = __shfl(tregC, (l + 1) & 63, 64);
                int cur  = (l == 63) ? tlastC : scur;
                int prev = tregC;
                if (l == 0 && cg == 0) prev = 30;      // START
                gold += s_tr[cur * 32 + prev];
            }
            if (cl < 1) tagload(cl + 1, tregN, tlastN);
        }

        // ---- stage d_t = exp(e_t) as fp8, half-permuted; gold pick ----
        {
            int trel = (blk & 7) * 8 + (l >> 3);
            int tshf = __shfl(tregC, (trel + 1) & 63, 64);
            int tgt  = (trel == 63) ? tlastC : tshf;
            if ((tgt >> 2) == (l & 7)) {
                int sub = tgt & 3;
                float ev = sub == 0 ? r0.x : sub == 1 ? r0.y : sub == 2 ? r0.z : r0.w;
                gold += ev;
            }
            float4 dv;
            dv.x = dexp2(r0.x * L2E); dv.y = dexp2(r0.y * L2E);
            dv.z = dexp2(r0.z * L2E); dv.w = dexp2(r0.w * L2E);
            unsigned u = (unsigned)__builtin_amdgcn_cvt_pk_fp8_f32(dv.x, dv.y, 0, false);
            u = (unsigned)__builtin_amdgcn_cvt_pk_fp8_f32(dv.z, dv.w, (int)u, true);
            int c = l & 7;
            s_d8[w * 64 + (l >> 3) * 8 + (c & 1) * 4 + (c >> 1)] = u;
        }
        r0 = r1; r1 = eload(blk + 2);

        if (blk < 4) {
            // ---- 8 matrix steps (R8-verbatim): acc <- E*(d o (s*acc)) ----
#pragma unroll
            for (int s = 0; s < 8; ++s) {
                const u32x4 rv = *(const u32x4*)(s_d8 + w * 64 + s * 8 + h * 4);
                unsigned bbn[8];
#pragma unroll
                for (int q2 = 0; q2 < 4; ++q2) {
                    f32x2 dlo = __builtin_amdgcn_cvt_pk_f32_fp8((int)rv[q2], false);
                    f32x2 dhi = __builtin_amdgcn_cvt_pk_f32_fp8((int)rv[q2], true);
                    f32x2 a0; a0.x = acc[4 * q2 + 0]; a0.y = acc[4 * q2 + 1];
                    f32x2 a1; a1.x = acc[4 * q2 + 2]; a1.y = acc[4 * q2 + 3];
                    f32x2 m0 = a0 * dlo;
                    f32x2 m1 = a1 * dhi;
                    if (s == 0 || s == 4) {
                        f32x2 sc; sc.x = s_cur; sc.y = s_cur;
                        m0 = m0 * sc; m1 = m1 * sc;
                    }
                    bbn[2 * q2]     = cvtpk(m0.x, m0.y);
                    bbn[2 * q2 + 1] = cvtpk(m1.x, m1.y);
                }
                if (s == 0 || s == 4) sigma += k_pend;
                bf16x8 B0 = __builtin_bit_cast(bf16x8, (u32x4){bbn[0], bbn[1], bbn[2], bbn[3]});
                bf16x8 B1 = __builtin_bit_cast(bf16x8, (u32x4){bbn[4], bbn[5], bbn[6], bbn[7]});
                f32x16 t = __builtin_amdgcn_mfma_f32_32x32x16_bf16(A0, B0, zro, 0, 0, 0);
                acc = __builtin_amdgcn_mfma_f32_32x32x16_bf16(A1, B1, t, 0, 0, 0);
                if (s == 3 || s == 7) {
                    unsigned eb = (__float_as_uint(acc[0]) >> 23) & 0xFF;
                    unsigned ku = (unsigned)__builtin_amdgcn_readfirstlane((int)eb);
                    k_pend = (int)ku - 127;
                    s_cur = __uint_as_float((254u - ku) << 23);
                }
            }
        } else {
            if (blk == 4) {
                // ---- Perron-safe handoff: R ~= u v^T, v = (1^T R)/(1^T R 1),
                //      u = R 1. (pending k_pend/s_cur discarded: we factor R
                //      itself; sigma stays consistent.)
                // w = 1^T R via ones-MFMA (A = ones is pi-invariant)
                unsigned bbh[8];
#pragma unroll
                for (int j = 0; j < 8; ++j) bbh[j] = pkrne(acc[2 * j], acc[2 * j + 1]);
                bf16x8 Bh0 = __builtin_bit_cast(bf16x8, (u32x4){bbh[0], bbh[1], bbh[2], bbh[3]});
                bf16x8 Bh1 = __builtin_bit_cast(bf16x8, (u32x4){bbh[4], bbh[5], bbh[6], bbh[7]});
                const unsigned OB = 0x3F803F80u;   // two bf16 1.0
                const bf16x8 Ao = __builtin_bit_cast(bf16x8, (u32x4){OB, OB, OB, OB});
                f32x16 t2 = __builtin_amdgcn_mfma_f32_32x32x16_bf16(Ao, Bh0, zro, 0, 0, 0);
                t2 = __builtin_amdgcn_mfma_f32_32x32x16_bf16(Ao, Bh1, t2, 0, 0, 0);
                float wq = t2[0];                  // w[q], same in every reg
                float ssum = wq;
                ssum += __shfl_xor(ssum, 1, 64);
                ssum += __shfl_xor(ssum, 2, 64);
                ssum += __shfl_xor(ssum, 4, 64);
                ssum += __shfl_xor(ssum, 8, 64);
                ssum += __shfl_xor(ssum, 16, 64);
                if (l < 32) s_v[w * 32 + q] = wq * __builtin_amdgcn_rcpf(ssum);
                // u = R*1 via cross-q shfl row sums
                float ur[16];
#pragma unroll
                for (int r = 0; r < 16; ++r) {
                    float t3 = acc[r];
                    t3 += __shfl_xor(t3, 1, 64);
                    t3 += __shfl_xor(t3, 2, 64);
                    t3 += __shfl_xor(t3, 4, 64);
                    t3 += __shfl_xor(t3, 8, 64);
                    t3 += __shfl_xor(t3, 16, 64);
                    ur[r] = t3;   // u[row(r,h)], uniform within half
                }
                if (q == 0) {
                    // rows for r=4p+k: 8p + 4h + k -> contiguous float4
#pragma unroll
                    for (int p = 0; p < 4; ++p) {
                        float4 vv;
                        vv.x = ur[4 * p + 0]; vv.y = ur[4 * p + 1];
                        vv.z = ur[4 * p + 2]; vv.w = ur[4 * p + 3];
                        *(float4*)(s_u + w * 32 + 8 * p + 4 * h) = vv;
                    }
                }
                u_own = s_u[w * 32 + q];
            }
            // ---- 8 vector steps: u <- E*(w), w = (d o u) * 2^-k (per-step
            //      wave-max normalize; k -> sigma). fp8 w, permuted layout.
#pragma unroll
            for (int s = 0; s < 8; ++s) {
                if (s == 7 && blk == 15 && w == 15) continue;  // global step 2048
                unsigned hd = s_d8[w * 64 + s * 8 + dhD];
                f32x2 dx = __builtin_amdgcn_cvt_pk_f32_fp8((int)(hd >> dhsh), false);
                float wv = dx.x * u_own;
                float mm = wv;
                mm = fmaxf(mm, __shfl_xor(mm, 1, 64));
                mm = fmaxf(mm, __shfl_xor(mm, 2, 64));
                mm = fmaxf(mm, __shfl_xor(mm, 4, 64));
                mm = fmaxf(mm, __shfl_xor(mm, 8, 64));
                mm = fmaxf(mm, __shfl_xor(mm, 16, 64));
                unsigned ku = (__float_as_uint(mm) >> 23) & 0xFF;
                sigma += (int)ku - 127;
                float wn = wv * __uint_as_float((254u - ku) << 23);  // max in [1,2)
                unsigned w8 = (unsigned)__builtin_amdgcn_cvt_pk_fp8_f32(wn, wn, 0, false);
                if (l < 32) s_w8[w * 32 + wperm] = (unsigned char)w8;
                const u32x4 W = *(const u32x4*)(s_w8 + w * 32 + 16 * h);
                f32x2 part; part.x = 0.f; part.y = 0.f;
#pragma unroll
                for (int g = 0; g < 4; ++g) {
                    f32x2 lo = __builtin_amdgcn_cvt_pk_f32_fp8((int)W[g], false);
                    f32x2 hi = __builtin_amdgcn_cvt_pk_f32_fp8((int)W[g], true);
                    part += efv[2 * g] * lo;        // cols match permuted layout
                    part += efv[2 * g + 1] * hi;
                }
                float p  = part.x + part.y;
                float po = __shfl_xor(p, 32, 64);   // other half's 16 cols
                u_own = p + po;
            }
        }
    }

    // ---- store final rank-1 factors ----
    if (l < 32) s_uf[w * 32 + q] = u_own;
    if (l == 0) s_base[w] = (float)sigma;

    // per-wave gold reduction
#pragma unroll
    for (int m = 1; m < 64; m <<= 1) gold += __shfl_xor(gold, m, 64);
    if (l == 0) s_gold[w] = gold;
    __syncthreads();

    // ---- phase 2: rank-1 chain x' = u_c * (v_c . x) * 2^sigma_c ----
    if (tid < 32) {
        int i = tid;
        float x  = dexp2(s_tr[i * 32 + 30] * L2E);   // tau_0 = E[:,START]
        float xb = 0.f;
        for (int c = 0; c < 16; ++c) {
            float t = s_v[c * 32 + i] * x;
#pragma unroll
            for (int m2 = 1; m2 < 32; m2 <<= 1) t += __shfl_xor(t, m2, 32);
            unsigned kb = (__float_as_uint(t) >> 23) & 0xFF;
            float tn = t * __uint_as_float((254u - kb) << 23);
            x = s_uf[c * 32 + i] * tn;
            xb += s_base[c] + (float)((int)kb - 127);
        }
        // final: Z = sum_i exp(tr[STOP,i] + e_2048[i]) * tau_2047[i]
        float elast = em[((size_t)b * 2048 + 2047) * 32 + i];
        float wv2 = dexp2((s_tr[31 * 32 + i] + elast) * L2E);
        float sv = x * wv2;
#pragma unroll
        for (int m2 = 1; m2 < 32; m2 <<= 1) sv += __shfl_xor(sv, m2, 32);
        float logZ = (xb + dlog2(sv)) * LN2;
        if (i == 0) {
            float g = 0.f;
#pragma unroll
            for (int wv3 = 0; wv3 < 16; ++wv3) g += s_gold[wv3];
            g += s_tr[31 * 32 + tgp[2047]];   // STOP term
            ws[b] = logZ - g;
        }
    }
}

// Deterministic fixed-order reduction of the 512 per-batch values.
__global__ __launch_bounds__(64) void crf_reduce_kernel(
    const float* __restrict__ ws, float* __restrict__ out)
{
    int l = threadIdx.x;
    float s = 0.f;
#pragma unroll
    for (int k = 0; k < 8; ++k) s += ws[l + k * 64];
    s += __shfl_xor(s, 1, 64);
    s += __shfl_xor(s, 2, 64);
    s += __shfl_xor(s, 4, 64);
    s += __shfl_xor(s, 8, 64);
    s += __shfl_xor(s, 16, 64);
    s += __shfl_xor(s, 32, 64);
    if (l == 0) out[0] = s;
}

extern "C" void kernel_launch(void* const* d_in, const int* in_sizes, int n_in,
                              void* d_out, int out_size, void* d_ws, size_t ws_size,
                              hipStream_t stream)
{
    const float* em = (const float*)d_in[0];
    const float* tr = (const float*)d_in[1];
    const int*   tg = (const int*)d_in[2];
    float* ws  = (float*)d_ws;
    float* out = (float*)d_out;

    hipLaunchKernelGGL(crf_phase_kernel, dim3(512), dim3(1024), 0, stream, em, tr, tg, ws);
    hipLaunchKernelGGL(crf_reduce_kernel, dim3(1), dim3(64), 0, stream, ws, out);
}

// Round 16
// 111.482 us; speedup vs baseline: 1.1959x; 1.1959x over previous
//
#include <hip/hip_runtime.h>

#define L2E 1.4426950408889634f
#define LN2 0.6931471805599453f

typedef float f32x16 __attribute__((ext_vector_type(16)));
typedef float f32x2  __attribute__((ext_vector_type(2)));
typedef short bf16x8 __attribute__((ext_vector_type(8)));
typedef unsigned int u32x4 __attribute__((ext_vector_type(4)));

__device__ __forceinline__ float dexp2(float x) { return __builtin_amdgcn_exp2f(x); }
__device__ __forceinline__ float dlog2(float x) { return __builtin_amdgcn_logf(x); }

// HW packed f32->2xbf16 (RNE). Inputs must be IR-produced VALU values
// (never raw MFMA accumulator regs) -- R3 post-mortem.
__device__ __forceinline__ unsigned cvtpk(float a, float b) {
    unsigned r;
    asm("v_cvt_pk_bf16_f32 %0, %1, %2" : "=v"(r) : "v"(a), "v"(b));
    return r;
}

// Software RNE pack (pure IR); low 16 bits = bf16(a).
__device__ __forceinline__ unsigned pkrne(float a, float b) {
    unsigned ua = __float_as_uint(a), ub = __float_as_uint(b);
    ua += 0x7FFFu + ((ua >> 16) & 1u);
    ub += 0x7FFFu + ((ub >> 16) & 1u);
    return __builtin_amdgcn_perm(ub, ua, 0x07060302u);
}

// DPP in-row reduction steps (ctrl must be a literal: builtin ICE arg).
// 0xB1 = quad_perm[1,0,3,2] (xor1), 0x4E = quad_perm[2,3,0,1] (xor2),
// 0x141 = row_half_mirror (8-group), 0x140 = row_mirror (16-group).
// Positive floats compare as unsigned ints -> DPPMAX is EXACT (bit-identical
// to the shfl_xor fmaxf chain it replaces). Sum order differs -> DPPADD only
// used in the once-per-chunk handoff (sub-ulp anchor shift, harmless).
#define DPPMAXU(m, ctrl) { \
    unsigned _t = (unsigned)__builtin_amdgcn_update_dpp(0, (int)(m), ctrl, 0xF, 0xF, true); \
    if (_t > (m)) (m) = _t; }
#define DPPADDF(x, ctrl) { \
    int _t = __builtin_amdgcn_update_dpp(0, __float_as_int(x), ctrl, 0xF, 0xF, true); \
    (x) += __int_as_float(_t); }

// CRF forward, rank-1 collapsed chunks — R14-PASS numerics preserved:
//   32 matrix steps -> Perron-safe factor R ~= u v^T (u = R*1, v ~ 1^T R)
//   -> 96 vector steps u <- E*(d o u), PER-STEP wave-max normalize of
//   w = d o u, fp8 w broadcast in permuted layout (1 ds_read_b128).
// R16 (perf-only, value-preserving): 5-shfl wave-max -> 4 DPP vmax + 1 shfl
// (exact same max; LDS-unit ops/step 8 -> ~3); d-dwords prefetched per blk;
// handoff reductions DPP-ified. R13/R15's 4-step-cadence+bf16 variant failed
// twice at identical absmax -> abandoned.
__global__ __launch_bounds__(1024, 4) void crf_phase_kernel(
    const float* __restrict__ em,   // [512][2048][32]
    const float* __restrict__ tr,   // [32][32] transitions[tag][prev]
    const int*   __restrict__ tgs,  // [512][2048]
    float*       __restrict__ ws)   // [512] per-batch nll
{
    __shared__ float s_tr[1024];                      // 4 KB
    __shared__ unsigned s_d8[16 * 64];                // 4 KB fp8 d staging
    __shared__ __align__(16) unsigned char s_w8[16 * 32];  // 512 B w broadcast
    __shared__ float s_u[16 * 32];                    // u handoff
    __shared__ float s_v[16 * 32];                    // v per chunk
    __shared__ float s_uf[16 * 32];                   // final u per chunk
    __shared__ float s_base[16];
    __shared__ float s_gold[16];

    const int tid = threadIdx.x;
    const int b   = blockIdx.x;
    const int w   = tid >> 6;    // wave = chunk index 0..15
    const int l   = tid & 63;
    const int h   = l >> 5;
    const int q   = l & 31;

    s_tr[tid & 1023] = tr[tid & 1023];
    __syncthreads();

    // A master: efv[j] = (E[q,col], E[q,col+1]), pi'd layout (R5-R8).
    f32x2 efv[8];
    unsigned ea[8];
#pragma unroll
    for (int j = 0; j < 8; ++j) {
        int k0  = 16 * (j >> 2) + 8 * h + 2 * (j & 3);
        int col = (k0 & ~12) | ((k0 & 4) << 1) | ((k0 & 8) >> 1);
        efv[j].x = dexp2(s_tr[q * 32 + col] * L2E);
        efv[j].y = dexp2(s_tr[q * 32 + col + 1] * L2E);
        ea[j] = pkrne(efv[j].x, efv[j].y);
    }
    const bf16x8 A0 = __builtin_bit_cast(bf16x8, (u32x4){ea[0], ea[1], ea[2], ea[3]});
    const bf16x8 A1 = __builtin_bit_cast(bf16x8, (u32x4){ea[4], ea[5], ea[6], ea[7]});

    f32x16 zro;
#pragma unroll
    for (int z = 0; z < 16; ++z) zro[z] = 0.f;

    const float* ebase = em + ((size_t)b * 2048 + (size_t)w * 128) * 32;
    const int*   tgp   = tgs + (size_t)b * 2048;

    // d[q] fetch: dword dhD of a slot, byte (q&3)
    const int dhD   = (q >> 3) + 4 * ((q >> 2) & 1);
    const int dhsh  = (q & 3) << 3;
    // w fp8 permuted write address: half ((q>>2)&1), dword (q>>3), byte (q&3)
    const int wperm = 16 * ((q >> 2) & 1) + 4 * (q >> 3) + (q & 3);

    f32x16 acc;
    float  s_cur = 1.f;
    int    k_pend = 0, sigma = 0;
    float  gold = 0.f;
    float  u_own = 0.f;
    float4 r0, r1;
    int    tregC = 0, tlastC = 0, tregN = 0, tlastN = 0;

#pragma unroll
    for (int r = 0; r < 16; ++r)
        acc[r] = ((((r & 3) + 8 * (r >> 2) + 4 * h) == q) ? 1.f : 0.f);

    auto eload = [&](int blk) -> float4 {
        int bb2 = blk > 15 ? 15 : blk;
        return *(const float4*)(ebase + ((bb2 * 8 + (l >> 3)) * 32 + (l & 7) * 4));
    };
    auto tagload = [&](int cl, int& treg, int& tlast) {
        int c0 = w * 128 + cl * 64;
        int idx = c0 - 1 + l; if (idx < 0) idx = 0;
        treg  = tgp[idx];
        tlast = tgp[c0 + 63];
    };

    r0 = eload(0); r1 = eload(1);
    tagload(0, tregC, tlastC);

#pragma unroll 1
    for (int blk = 0; blk < 16; ++blk) {
        if ((blk & 7) == 0) {
            int cl = blk >> 3;
            int cg = w * 2 + cl;
            if (cl > 0) { tregC = tregN; tlastC = tlastN; }
            {   // gold transition terms for this 64-group
                int scur = __shfl(tregC, (l + 1) & 63, 64);
                int cur  = (l == 63) ? tlastC : scur;
                int prev = tregC;
                if (l == 0 && cg == 0) prev = 30;      // START
                gold += s_tr[cur * 32 + prev];
            }
            if (cl < 1) tagload(cl + 1, tregN, tlastN);
        }

        // ---- stage d_t = exp(e_t) as fp8, half-permuted; gold pick ----
        {
            int trel = (blk & 7) * 8 + (l >> 3);
            int tshf = __shfl(tregC, (trel + 1) & 63, 64);
            int tgt  = (trel == 63) ? tlastC : tshf;
            if ((tgt >> 2) == (l & 7)) {
                int sub = tgt & 3;
                float ev = sub == 0 ? r0.x : sub == 1 ? r0.y : sub == 2 ? r0.z : r0.w;
                gold += ev;
            }
            float4 dv;
            dv.x = dexp2(r0.x * L2E); dv.y = dexp2(r0.y * L2E);
            dv.z = dexp2(r0.z * L2E); dv.w = dexp2(r0.w * L2E);
            unsigned u = (unsigned)__builtin_amdgcn_cvt_pk_fp8_f32(dv.x, dv.y, 0, false);
            u = (unsigned)__builtin_amdgcn_cvt_pk_fp8_f32(dv.z, dv.w, (int)u, true);
            int c = l & 7;
            s_d8[w * 64 + (l >> 3) * 8 + (c & 1) * 4 + (c >> 1)] = u;
        }
        r0 = r1; r1 = eload(blk + 2);

        if (blk < 4) {
            // ---- 8 matrix steps (R8-verbatim): acc <- E*(d o (s*acc)) ----
#pragma unroll
            for (int s = 0; s < 8; ++s) {
                const u32x4 rv = *(const u32x4*)(s_d8 + w * 64 + s * 8 + h * 4);
                unsigned bbn[8];
#pragma unroll
                for (int q2 = 0; q2 < 4; ++q2) {
                    f32x2 dlo = __builtin_amdgcn_cvt_pk_f32_fp8((int)rv[q2], false);
                    f32x2 dhi = __builtin_amdgcn_cvt_pk_f32_fp8((int)rv[q2], true);
                    f32x2 a0; a0.x = acc[4 * q2 + 0]; a0.y = acc[4 * q2 + 1];
                    f32x2 a1; a1.x = acc[4 * q2 + 2]; a1.y = acc[4 * q2 + 3];
                    f32x2 m0 = a0 * dlo;
                    f32x2 m1 = a1 * dhi;
                    if (s == 0 || s == 4) {
                        f32x2 sc; sc.x = s_cur; sc.y = s_cur;
                        m0 = m0 * sc; m1 = m1 * sc;
                    }
                    bbn[2 * q2]     = cvtpk(m0.x, m0.y);
                    bbn[2 * q2 + 1] = cvtpk(m1.x, m1.y);
                }
                if (s == 0 || s == 4) sigma += k_pend;
                bf16x8 B0 = __builtin_bit_cast(bf16x8, (u32x4){bbn[0], bbn[1], bbn[2], bbn[3]});
                bf16x8 B1 = __builtin_bit_cast(bf16x8, (u32x4){bbn[4], bbn[5], bbn[6], bbn[7]});
                f32x16 t = __builtin_amdgcn_mfma_f32_32x32x16_bf16(A0, B0, zro, 0, 0, 0);
                acc = __builtin_amdgcn_mfma_f32_32x32x16_bf16(A1, B1, t, 0, 0, 0);
                if (s == 3 || s == 7) {
                    unsigned eb = (__float_as_uint(acc[0]) >> 23) & 0xFF;
                    unsigned ku = (unsigned)__builtin_amdgcn_readfirstlane((int)eb);
                    k_pend = (int)ku - 127;
                    s_cur = __uint_as_float((254u - ku) << 23);
                }
            }
        } else {
            if (blk == 4) {
                // ---- Perron-safe handoff: u = R*1, v ~ 1^T R (DPP sums) ----
                unsigned bbh[8];
#pragma unroll
                for (int j = 0; j < 8; ++j) bbh[j] = pkrne(acc[2 * j], acc[2 * j + 1]);
                bf16x8 Bh0 = __builtin_bit_cast(bf16x8, (u32x4){bbh[0], bbh[1], bbh[2], bbh[3]});
                bf16x8 Bh1 = __builtin_bit_cast(bf16x8, (u32x4){bbh[4], bbh[5], bbh[6], bbh[7]});
                const unsigned OB = 0x3F803F80u;   // two bf16 1.0
                const bf16x8 Ao = __builtin_bit_cast(bf16x8, (u32x4){OB, OB, OB, OB});
                f32x16 t2 = __builtin_amdgcn_mfma_f32_32x32x16_bf16(Ao, Bh0, zro, 0, 0, 0);
                t2 = __builtin_amdgcn_mfma_f32_32x32x16_bf16(Ao, Bh1, t2, 0, 0, 0);
                float wq = t2[0];                  // w[q] = col-sum q
                float ssum = wq;
                DPPADDF(ssum, 0xB1) DPPADDF(ssum, 0x4E)
                DPPADDF(ssum, 0x141) DPPADDF(ssum, 0x140)
                ssum += __shfl_xor(ssum, 16, 64);
                if (l < 32) s_v[w * 32 + q] = wq * __builtin_amdgcn_rcpf(ssum);
                float ur[16];
#pragma unroll
                for (int r = 0; r < 16; ++r) {
                    float t3 = acc[r];
                    DPPADDF(t3, 0xB1) DPPADDF(t3, 0x4E)
                    DPPADDF(t3, 0x141) DPPADDF(t3, 0x140)
                    t3 += __shfl_xor(t3, 16, 64);
                    ur[r] = t3;   // u[row(r,h)], uniform within half
                }
                if (q == 0) {
#pragma unroll
                    for (int p = 0; p < 4; ++p) {
                        float4 vv;
                        vv.x = ur[4 * p + 0]; vv.y = ur[4 * p + 1];
                        vv.z = ur[4 * p + 2]; vv.w = ur[4 * p + 3];
                        *(float4*)(s_u + w * 32 + 8 * p + 4 * h) = vv;
                    }
                }
                u_own = s_u[w * 32 + q];
            }
            // ---- prefetch this block's 8 d-dwords (same values, off path) ----
            unsigned dr[8];
#pragma unroll
            for (int s = 0; s < 8; ++s) dr[s] = s_d8[w * 64 + s * 8 + dhD];
            // ---- 8 vector steps (R14-bit-identical): u <- E*(w),
            //      w = (d o u)*2^-k, k = wave-max exponent (DPP max) ----
#pragma unroll
            for (int s = 0; s < 8; ++s) {
                if (s == 7 && blk == 15 && w == 15) continue;  // global step 2048
                f32x2 dx = __builtin_amdgcn_cvt_pk_f32_fp8((int)(dr[s] >> dhsh), false);
                float wv = dx.x * u_own;
                unsigned m = __float_as_uint(wv);   // positive: uint cmp == float cmp
                DPPMAXU(m, 0xB1) DPPMAXU(m, 0x4E)
                DPPMAXU(m, 0x141) DPPMAXU(m, 0x140)
                {
                    unsigned o16 = (unsigned)__shfl_xor((int)m, 16, 64);
                    if (o16 > m) m = o16;
                }
                unsigned ku = (m >> 23) & 0xFF;
                sigma += (int)ku - 127;
                float wn = wv * __uint_as_float((254u - ku) << 23);  // max in [1,2)
                unsigned w8 = (unsigned)__builtin_amdgcn_cvt_pk_fp8_f32(wn, wn, 0, false);
                if (l < 32) s_w8[w * 32 + wperm] = (unsigned char)w8;
                const u32x4 W = *(const u32x4*)(s_w8 + w * 32 + 16 * h);
                f32x2 part; part.x = 0.f; part.y = 0.f;
#pragma unroll
                for (int g = 0; g < 4; ++g) {
                    f32x2 lo = __builtin_amdgcn_cvt_pk_f32_fp8((int)W[g], false);
                    f32x2 hi = __builtin_amdgcn_cvt_pk_f32_fp8((int)W[g], true);
                    part += efv[2 * g] * lo;        // cols match permuted layout
                    part += efv[2 * g + 1] * hi;
                }
                float p  = part.x + part.y;
                float po = __shfl_xor(p, 32, 64);   // other half's 16 cols
                u_own = p + po;
            }
        }
    }

    // ---- store final rank-1 factors ----
    if (l < 32) s_uf[w * 32 + q] = u_own;
    if (l == 0) s_base[w] = (float)sigma;

    // per-wave gold reduction
#pragma unroll
    for (int m = 1; m < 64; m <<= 1) gold += __shfl_xor(gold, m, 64);
    if (l == 0) s_gold[w] = gold;
    __syncthreads();

    // ---- phase 2: rank-1 chain x' = u_c * (v_c . x) * 2^sigma_c ----
    if (tid < 32) {
        int i = tid;
        float x  = dexp2(s_tr[i * 32 + 30] * L2E);   // tau_0 = E[:,START]
        float xb = 0.f;
        for (int c = 0; c < 16; ++c) {
            float t = s_v[c * 32 + i] * x;
#pragma unroll
            for (int m2 = 1; m2 < 32; m2 <<= 1) t += __shfl_xor(t, m2, 32);
            unsigned kb = (__float_as_uint(t) >> 23) & 0xFF;
            float tn = t * __uint_as_float((254u - kb) << 23);
            x = s_uf[c * 32 + i] * tn;
            xb += s_base[c] + (float)((int)kb - 127);
        }
        // final: Z = sum_i exp(tr[STOP,i] + e_2048[i]) * tau_2047[i]
        float elast = em[((size_t)b * 2048 + 2047) * 32 + i];
        float wv2 = dexp2((s_tr[31 * 32 + i] + elast) * L2E);
        float sv = x * wv2;
#pragma unroll
        for (int m2 = 1; m2 < 32; m2 <<= 1) sv += __shfl_xor(sv, m2, 32);
        float logZ = (xb + dlog2(sv)) * LN2;
        if (i == 0) {
            float g = 0.f;
#pragma unroll
            for (int wv3 = 0; wv3 < 16; ++wv3) g += s_gold[wv3];
            g += s_tr[31 * 32 + tgp[2047]];   // STOP term
            ws[b] = logZ - g;
        }
    }
}

// Deterministic fixed-order reduction of the 512 per-batch values.
__global__ __launch_bounds__(64) void crf_reduce_kernel(
    const float* __restrict__ ws, float* __restrict__ out)
{
    int l = threadIdx.x;
    float s = 0.f;
#pragma unroll
    for (int k = 0; k < 8; ++k) s += ws[l + k * 64];
    s += __shfl_xor(s, 1, 64);
    s += __shfl_xor(s, 2, 64);
    s += __shfl_xor(s, 4, 64);
    s += __shfl_xor(s, 8, 64);
    s += __shfl_xor(s, 16, 64);
    s += __shfl_xor(s, 32, 64);
    if (l == 0) out[0] = s;
}

extern "C" void kernel_launch(void* const* d_in, const int* in_sizes, int n_in,
                              void* d_out, int out_size, void* d_ws, size_t ws_size,
                              hipStream_t stream)
{
    const float* em = (const float*)d_in[0];
    const float* tr = (const float*)d_in[1];
    const int*   tg = (const int*)d_in[2];
    float* ws  = (float*)d_ws;
    float* out = (float*)d_out;

    hipLaunchKernelGGL(crf_phase_kernel, dim3(512), dim3(1024), 0, stream, em, tr, tg, ws);
    hipLaunchKernelGGL(crf_reduce_kernel, dim3(1), dim3(64), 0, stream, ws, out);
}

// Round 17
// 106.573 us; speedup vs baseline: 1.2510x; 1.0461x over previous
//
#include <hip/hip_runtime.h>

#define L2E 1.4426950408889634f
#define LN2 0.6931471805599453f

typedef float f32x16 __attribute__((ext_vector_type(16)));
typedef float f32x2  __attribute__((ext_vector_type(2)));
typedef short bf16x8 __attribute__((ext_vector_type(8)));
typedef unsigned int u32x4 __attribute__((ext_vector_type(4)));

__device__ __forceinline__ float dexp2(float x) { return __builtin_amdgcn_exp2f(x); }
__device__ __forceinline__ float dlog2(float x) { return __builtin_amdgcn_logf(x); }

// HW packed f32->2xbf16 (RNE). Inputs must be IR-produced VALU values
// (never raw MFMA accumulator regs) -- R3 post-mortem.
__device__ __forceinline__ unsigned cvtpk(float a, float b) {
    unsigned r;
    asm("v_cvt_pk_bf16_f32 %0, %1, %2" : "=v"(r) : "v"(a), "v"(b));
    return r;
}

// Software RNE pack (pure IR); low 16 bits = bf16(a).
__device__ __forceinline__ unsigned pkrne(float a, float b) {
    unsigned ua = __float_as_uint(a), ub = __float_as_uint(b);
    ua += 0x7FFFu + ((ua >> 16) & 1u);
    ub += 0x7FFFu + ((ub >> 16) & 1u);
    return __builtin_amdgcn_perm(ub, ua, 0x07060302u);
}

// DPP reduction steps (ctrl literal: builtin ICE arg). Positive floats
// compare as uints -> DPPMAXU exact. DPPADDF only in once-per-chunk handoff.
#define DPPMAXU(m, ctrl) { \
    unsigned _t = (unsigned)__builtin_amdgcn_update_dpp(0, (int)(m), ctrl, 0xF, 0xF, true); \
    if (_t > (m)) (m) = _t; }
#define DPPADDF(x, ctrl) { \
    int _t = __builtin_amdgcn_update_dpp(0, __float_as_int(x), ctrl, 0xF, 0xF, true); \
    (x) += __int_as_float(_t); }

// CRF forward, rank-1 collapsed chunks, DUAL-BATCH interleaved (ILP=2):
// R16's vector step has ~580cyc serial latency (shfl16 + w LDS round-trip +
// shfl32) with only ~3.4 waves/SIMD -> ~286cyc/step-slot wall. Each wave now
// runs chunk w of TWO batches, steps interleaved -> 2 independent chains
// fill each other's stalls. Per-chain numerics bit-identical to R16-PASS.
__global__ __launch_bounds__(1024, 4) void crf_phase_kernel(
    const float* __restrict__ em,   // [512][2048][32]
    const float* __restrict__ tr,   // [32][32] transitions[tag][prev]
    const int*   __restrict__ tgs,  // [512][2048]
    float*       __restrict__ ws)   // [512] per-batch nll
{
    __shared__ float s_tr[1024];                        // 4 KB
    __shared__ unsigned s_d8[2][16 * 64];               // 8 KB fp8 d staging
    __shared__ __align__(16) unsigned char s_w8[2][16 * 32];  // 1 KB w bcast
    __shared__ float s_u[16 * 32];                      // handoff scratch
    __shared__ float s_v[2][16 * 32];                   // v per chunk
    __shared__ float s_uf[2][16 * 32];                  // final u per chunk
    __shared__ float s_base[2][16];
    __shared__ float s_gold[2][16];

    const int tid = threadIdx.x;
    const int b0  = blockIdx.x * 2;
    const int w   = tid >> 6;    // wave = chunk index 0..15
    const int l   = tid & 63;
    const int h   = l >> 5;
    const int q   = l & 31;

    s_tr[tid & 1023] = tr[tid & 1023];
    __syncthreads();

    // A master: efv[j] = (E[q,col], E[q,col+1]), pi'd layout (R5-R8).
    f32x2 efv[8];
    unsigned ea[8];
#pragma unroll
    for (int j = 0; j < 8; ++j) {
        int k0  = 16 * (j >> 2) + 8 * h + 2 * (j & 3);
        int col = (k0 & ~12) | ((k0 & 4) << 1) | ((k0 & 8) >> 1);
        efv[j].x = dexp2(s_tr[q * 32 + col] * L2E);
        efv[j].y = dexp2(s_tr[q * 32 + col + 1] * L2E);
        ea[j] = pkrne(efv[j].x, efv[j].y);
    }
    const bf16x8 A0 = __builtin_bit_cast(bf16x8, (u32x4){ea[0], ea[1], ea[2], ea[3]});
    const bf16x8 A1 = __builtin_bit_cast(bf16x8, (u32x4){ea[4], ea[5], ea[6], ea[7]});

    f32x16 zro;
#pragma unroll
    for (int z = 0; z < 16; ++z) zro[z] = 0.f;

    const float* ebA = em + ((size_t)b0 * 2048 + (size_t)w * 128) * 32;
    const float* ebB = ebA + (size_t)2048 * 32;
    const int*   tgA = tgs + (size_t)b0 * 2048;
    const int*   tgB = tgA + 2048;

    const int dhD   = (q >> 3) + 4 * ((q >> 2) & 1);
    const int dhsh  = (q & 3) << 3;
    const int wperm = 16 * ((q >> 2) & 1) + 4 * (q >> 3) + (q & 3);

    f32x16 accA, accB;
    float  scA = 1.f, scB = 1.f;
    int    kpA = 0, kpB = 0, sgA = 0, sgB = 0;
    float  goldA = 0.f, goldB = 0.f;
    float  uA = 0.f, uB = 0.f;
    float4 r0A, r0B;
    int    trA = 0, tlA = 0, trB = 0, tlB = 0;
    int    trAn = 0, tlAn = 0, trBn = 0, tlBn = 0;

#pragma unroll
    for (int r = 0; r < 16; ++r) {
        float iv = ((((r & 3) + 8 * (r >> 2) + 4 * h) == q) ? 1.f : 0.f);
        accA[r] = iv; accB[r] = iv;
    }

    auto eload = [&](const float* eb, int blk) -> float4 {
        int k = blk > 15 ? 15 : blk;
        return *(const float4*)(eb + ((k * 8 + (l >> 3)) * 32 + (l & 7) * 4));
    };
    auto tagload = [&](const int* tgp, int cl, int& treg, int& tlast) {
        int c0 = w * 128 + cl * 64;
        int idx = c0 - 1 + l; if (idx < 0) idx = 0;
        treg  = tgp[idx];
        tlast = tgp[c0 + 63];
    };
    auto handoff = [&](const f32x16& ACC, float& UOWN, int vb) {
        // Perron-safe: v ~ 1^T R (ones-MFMA), u = R*1 (DPP row sums)
        unsigned bbh[8];
#pragma unroll
        for (int j = 0; j < 8; ++j) bbh[j] = pkrne(ACC[2 * j], ACC[2 * j + 1]);
        bf16x8 Bh0 = __builtin_bit_cast(bf16x8, (u32x4){bbh[0], bbh[1], bbh[2], bbh[3]});
        bf16x8 Bh1 = __builtin_bit_cast(bf16x8, (u32x4){bbh[4], bbh[5], bbh[6], bbh[7]});
        const unsigned OB = 0x3F803F80u;   // two bf16 1.0
        const bf16x8 Ao = __builtin_bit_cast(bf16x8, (u32x4){OB, OB, OB, OB});
        f32x16 t2 = __builtin_amdgcn_mfma_f32_32x32x16_bf16(Ao, Bh0, zro, 0, 0, 0);
        t2 = __builtin_amdgcn_mfma_f32_32x32x16_bf16(Ao, Bh1, t2, 0, 0, 0);
        float wq = t2[0];
        float ssum = wq;
        DPPADDF(ssum, 0xB1) DPPADDF(ssum, 0x4E)
        DPPADDF(ssum, 0x141) DPPADDF(ssum, 0x140)
        ssum += __shfl_xor(ssum, 16, 64);
        if (l < 32) s_v[vb][w * 32 + q] = wq * __builtin_amdgcn_rcpf(ssum);
        float ur[16];
#pragma unroll
        for (int r = 0; r < 16; ++r) {
            float t3 = ACC[r];
            DPPADDF(t3, 0xB1) DPPADDF(t3, 0x4E)
            DPPADDF(t3, 0x141) DPPADDF(t3, 0x140)
            t3 += __shfl_xor(t3, 16, 64);
            ur[r] = t3;
        }
        if (q == 0) {
#pragma unroll
            for (int p = 0; p < 4; ++p) {
                float4 vv;
                vv.x = ur[4 * p + 0]; vv.y = ur[4 * p + 1];
                vv.z = ur[4 * p + 2]; vv.w = ur[4 * p + 3];
                *(float4*)(s_u + w * 32 + 8 * p + 4 * h) = vv;
            }
        }
        UOWN = s_u[w * 32 + q];
    };

    r0A = eload(ebA, 0); r0B = eload(ebB, 0);
    tagload(tgA, 0, trA, tlA);
    tagload(tgB, 0, trB, tlB);

#pragma unroll 1
    for (int blk = 0; blk < 16; ++blk) {
        if ((blk & 7) == 0) {
            int cl = blk >> 3;
            int cg = w * 2 + cl;
            if (cl > 0) { trA = trAn; tlA = tlAn; trB = trBn; tlB = tlBn; }
            {   // gold transition terms, both chains
                int sA = __shfl(trA, (l + 1) & 63, 64);
                int cA = (l == 63) ? tlA : sA;
                int pA = trA;
                int sB = __shfl(trB, (l + 1) & 63, 64);
                int cB = (l == 63) ? tlB : sB;
                int pB = trB;
                if (l == 0 && cg == 0) { pA = 30; pB = 30; }   // START
                goldA += s_tr[cA * 32 + pA];
                goldB += s_tr[cB * 32 + pB];
            }
            if (cl < 1) { tagload(tgA, 1, trAn, tlAn); tagload(tgB, 1, trBn, tlBn); }
        }

        // ---- stage d = exp(e) as fp8 (both chains); gold picks ----
#define STAGE(BANK, R0, TRX, TLX, GOLD) do { \
            int trel = (blk & 7) * 8 + (l >> 3); \
            int tshf = __shfl(TRX, (trel + 1) & 63, 64); \
            int tgt  = (trel == 63) ? TLX : tshf; \
            if ((tgt >> 2) == (l & 7)) { \
                int sub = tgt & 3; \
                GOLD += sub == 0 ? R0.x : sub == 1 ? R0.y : sub == 2 ? R0.z : R0.w; \
            } \
            float4 dv; \
            dv.x = dexp2(R0.x * L2E); dv.y = dexp2(R0.y * L2E); \
            dv.z = dexp2(R0.z * L2E); dv.w = dexp2(R0.w * L2E); \
            unsigned uu = (unsigned)__builtin_amdgcn_cvt_pk_fp8_f32(dv.x, dv.y, 0, false); \
            uu = (unsigned)__builtin_amdgcn_cvt_pk_fp8_f32(dv.z, dv.w, (int)uu, true); \
            int c = l & 7; \
            s_d8[BANK][w * 64 + (l >> 3) * 8 + (c & 1) * 4 + (c >> 1)] = uu; \
} while (0)
        STAGE(0, r0A, trA, tlA, goldA);
        STAGE(1, r0B, trB, tlB, goldB);
#undef STAGE
        r0A = eload(ebA, blk + 1);
        r0B = eload(ebB, blk + 1);

        if (blk < 4) {
            // ---- 8 matrix steps x 2 chains, interleaved ----
#pragma unroll
            for (int s = 0; s < 8; ++s) {
#define MSTEP(BANK, ACC, SCUR, KPEND, SIGMA) do { \
                const u32x4 rv = *(const u32x4*)(&s_d8[BANK][w * 64 + s * 8 + h * 4]); \
                unsigned bbn[8]; \
                _Pragma("unroll") for (int q2 = 0; q2 < 4; ++q2) { \
                    f32x2 dlo = __builtin_amdgcn_cvt_pk_f32_fp8((int)rv[q2], false); \
                    f32x2 dhi = __builtin_amdgcn_cvt_pk_f32_fp8((int)rv[q2], true); \
                    f32x2 a0; a0.x = ACC[4 * q2 + 0]; a0.y = ACC[4 * q2 + 1]; \
                    f32x2 a1; a1.x = ACC[4 * q2 + 2]; a1.y = ACC[4 * q2 + 3]; \
                    f32x2 m0 = a0 * dlo; \
                    f32x2 m1 = a1 * dhi; \
                    if (s == 0 || s == 4) { \
                        f32x2 sc; sc.x = SCUR; sc.y = SCUR; \
                        m0 = m0 * sc; m1 = m1 * sc; \
                    } \
                    bbn[2 * q2]     = cvtpk(m0.x, m0.y); \
                    bbn[2 * q2 + 1] = cvtpk(m1.x, m1.y); \
                } \
                if (s == 0 || s == 4) SIGMA += KPEND; \
                bf16x8 B0 = __builtin_bit_cast(bf16x8, (u32x4){bbn[0], bbn[1], bbn[2], bbn[3]}); \
                bf16x8 B1 = __builtin_bit_cast(bf16x8, (u32x4){bbn[4], bbn[5], bbn[6], bbn[7]}); \
                f32x16 t = __builtin_amdgcn_mfma_f32_32x32x16_bf16(A0, B0, zro, 0, 0, 0); \
                ACC = __builtin_amdgcn_mfma_f32_32x32x16_bf16(A1, B1, t, 0, 0, 0); \
                if (s == 3 || s == 7) { \
                    unsigned eb2 = (__float_as_uint(ACC[0]) >> 23) & 0xFF; \
                    unsigned ku = (unsigned)__builtin_amdgcn_readfirstlane((int)eb2); \
                    KPEND = (int)ku - 127; \
                    SCUR = __uint_as_float((254u - ku) << 23); \
                } \
} while (0)
                MSTEP(0, accA, scA, kpA, sgA);
                MSTEP(1, accB, scB, kpB, sgB);
#undef MSTEP
            }
        } else {
            if (blk == 4) { handoff(accA, uA, 0); handoff(accB, uB, 1); }
            // prefetch this block's d-dwords for both chains
            unsigned drA[8], drB[8];
#pragma unroll
            for (int s = 0; s < 8; ++s) {
                drA[s] = s_d8[0][w * 64 + s * 8 + dhD];
                drB[s] = s_d8[1][w * 64 + s * 8 + dhD];
            }
            // ---- 8 vector steps x 2 chains, interleaved (R16-bit-identical
            //      per chain): u <- E*(w), w = (d o u)*2^-k, k = wave-max ----
#pragma unroll
            for (int s = 0; s < 8; ++s) {
                if (s == 7 && blk == 15 && w == 15) continue;  // step 2048, both
#define VSTEP(BANK, UOWN, SIGMA, DRS) do { \
                f32x2 dx = __builtin_amdgcn_cvt_pk_f32_fp8((int)((DRS) >> dhsh), false); \
                float wv = dx.x * UOWN; \
                unsigned m = __float_as_uint(wv); \
                DPPMAXU(m, 0xB1) DPPMAXU(m, 0x4E) \
                DPPMAXU(m, 0x141) DPPMAXU(m, 0x140) \
                { \
                    unsigned o16 = (unsigned)__shfl_xor((int)m, 16, 64); \
                    if (o16 > m) m = o16; \
                } \
                unsigned ku = (m >> 23) & 0xFF; \
                SIGMA += (int)ku - 127; \
                float wn = wv * __uint_as_float((254u - ku) << 23); \
                unsigned w8 = (unsigned)__builtin_amdgcn_cvt_pk_fp8_f32(wn, wn, 0, false); \
                if (l < 32) s_w8[BANK][w * 32 + wperm] = (unsigned char)w8; \
                const u32x4 W = *(const u32x4*)(&s_w8[BANK][w * 32 + 16 * h]); \
                f32x2 part; part.x = 0.f; part.y = 0.f; \
                _Pragma("unroll") for (int g2 = 0; g2 < 4; ++g2) { \
                    f32x2 lo = __builtin_amdgcn_cvt_pk_f32_fp8((int)W[g2], false); \
                    f32x2 hi = __builtin_amdgcn_cvt_pk_f32_fp8((int)W[g2], true); \
                    part += efv[2 * g2] * lo; \
                    part += efv[2 * g2 + 1] * hi; \
                } \
                float p  = part.x + part.y; \
                float po = __shfl_xor(p, 32, 64); \
                UOWN = p + po; \
} while (0)
                VSTEP(0, uA, sgA, drA[s]);
                VSTEP(1, uB, sgB, drB[s]);
#undef VSTEP
            }
        }
    }

    // ---- store final rank-1 factors (both chains) ----
    if (l < 32) { s_uf[0][w * 32 + q] = uA; s_uf[1][w * 32 + q] = uB; }
    if (l == 0) { s_base[0][w] = (float)sgA; s_base[1][w] = (float)sgB; }

    // per-wave gold reductions
#pragma unroll
    for (int m = 1; m < 64; m <<= 1) goldA += __shfl_xor(goldA, m, 64);
#pragma unroll
    for (int m = 1; m < 64; m <<= 1) goldB += __shfl_xor(goldB, m, 64);
    if (l == 0) { s_gold[0][w] = goldA; s_gold[1][w] = goldB; }
    __syncthreads();

    // ---- phase 2: lanes 0..31 batch A, lanes 32..63 batch B ----
    if (tid < 64) {
        int h2 = tid >> 5;
        int i  = tid & 31;
        const int* tgp = h2 ? tgB : tgA;
        float x  = dexp2(s_tr[i * 32 + 30] * L2E);   // tau_0 = E[:,START]
        float xb = 0.f;
        for (int c = 0; c < 16; ++c) {
            float t = s_v[h2][c * 32 + i] * x;
#pragma unroll
            for (int m2 = 1; m2 < 32; m2 <<= 1) t += __shfl_xor(t, m2, 32);
            unsigned kb = (__float_as_uint(t) >> 23) & 0xFF;
            float tn = t * __uint_as_float((254u - kb) << 23);
            x = s_uf[h2][c * 32 + i] * tn;
            xb += s_base[h2][c] + (float)((int)kb - 127);
        }
        // final: Z = sum_i exp(tr[STOP,i] + e_2048[i]) * tau_2047[i]
        float elast = em[((size_t)(b0 + h2) * 2048 + 2047) * 32 + i];
        float wv2 = dexp2((s_tr[31 * 32 + i] + elast) * L2E);
        float sv = x * wv2;
#pragma unroll
        for (int m2 = 1; m2 < 32; m2 <<= 1) sv += __shfl_xor(sv, m2, 32);
        float logZ = (xb + dlog2(sv)) * LN2;
        if (i == 0) {
            float g = 0.f;
#pragma unroll
            for (int wv3 = 0; wv3 < 16; ++wv3) g += s_gold[h2][wv3];
            g += s_tr[31 * 32 + tgp[2047]];   // STOP term
            ws[b0 + h2] = logZ - g;
        }
    }
}

// Deterministic fixed-order reduction of the 512 per-batch values.
__global__ __launch_bounds__(64) void crf_reduce_kernel(
    const float* __restrict__ ws, float* __restrict__ out)
{
    int l = threadIdx.x;
    float s = 0.f;
#pragma unroll
    for (int k = 0; k < 8; ++k) s += ws[l + k * 64];
    s += __shfl_xor(s, 1, 64);
    s += __shfl_xor(s, 2, 64);
    s += __shfl_xor(s, 4, 64);
    s += __shfl_xor(s, 8, 64);
    s += __shfl_xor(s, 16, 64);
    s += __shfl_xor(s, 32, 64);
    if (l == 0) out[0] = s;
}

extern "C" void kernel_launch(void* const* d_in, const int* in_sizes, int n_in,
                              void* d_out, int out_size, void* d_ws, size_t ws_size,
                              hipStream_t stream)
{
    const float* em = (const float*)d_in[0];
    const float* tr = (const float*)d_in[1];
    const int*   tg = (const int*)d_in[2];
    float* ws  = (float*)d_ws;
    float* out = (float*)d_out;

    hipLaunchKernelGGL(crf_phase_kernel, dim3(256), dim3(1024), 0, stream, em, tr, tg, ws);
    hipLaunchKernelGGL(crf_reduce_kernel, dim3(1), dim3(64), 0, stream, ws, out);
}